// Round 12
// baseline (1165.824 us; speedup 1.0000x reference)
//
#include <hip/hip_runtime.h>
#include <hip/hip_bf16.h>

// Llama attention block: B=2, S=2048, H=4096, NH=32, NKV=8, HD=128, GQA 4:1.
// Pipeline (bf16 MFMA, fp32 accumulate):
//   1. convert hidden -> bf16; Wq/Wk/Wv -> bf16 in one dispatch
//   2. QKV = X @ Wqkv^T  (256^2 8-phase GEMM, compiler-scheduled — r10 best)
//   3. RoPE (Q,K) + scatter; fold 1/sqrt(128) into Q
//   4. V transpose: QKV -> Vtg [b][hkv][128 d][2048 s]
//   5. flash attention (causal): KVBLK=64 (r5 structure), SINGLE-buffered
//      K/V LDS (48 KiB) -> 3 blocks/CU for TLP
//   6. out = AttnOut @ Wo^T (fp32), same GEMM

typedef __bf16 bf16;
typedef __bf16 bf16x8 __attribute__((ext_vector_type(8)));
typedef float f32x4 __attribute__((ext_vector_type(4)));

#define UNROLL _Pragma("unroll")

__device__ __forceinline__ void async16(const bf16* g, bf16* l) {
  __builtin_amdgcn_global_load_lds(
      (const __attribute__((address_space(1))) void*)g,
      (__attribute__((address_space(3))) void*)l,
      16, 0, 0);
}

#define BARR { __builtin_amdgcn_s_barrier(); }
#define VMCNT(n) { asm volatile("s_waitcnt vmcnt(" #n ")" ::: "memory"); }

// ---------------- fp32 -> bf16 convert (8 elem/thread) ----------------
__global__ void k_cvt(const float* __restrict__ s, bf16* __restrict__ d, int n8) {
  int i = blockIdx.x * 256 + threadIdx.x;
  if (i >= n8) return;
  const float4* sp = (const float4*)s + (size_t)i * 2;
  float4 a = sp[0], b = sp[1];
  bf16x8 o = { (bf16)a.x, (bf16)a.y, (bf16)a.z, (bf16)a.w,
               (bf16)b.x, (bf16)b.y, (bf16)b.z, (bf16)b.w };
  *(bf16x8*)(d + (size_t)i * 8) = o;
}

// ---------------- Wq/Wk/Wv converts in one dispatch ----------------------
__global__ void k_cvtw3(const float* __restrict__ Wq, const float* __restrict__ Wk,
                        const float* __restrict__ Wv, bf16* __restrict__ Wqkv) {
  int u = blockIdx.x * 256 + threadIdx.x;
  const float* sp;
  bf16* dp;
  size_t off;
  if (u < 2097152) { sp = Wq; dp = Wqkv; off = u; }
  else if (u < 2621440) { sp = Wk; dp = Wqkv + 16777216u; off = u - 2097152; }
  else { sp = Wv; dp = Wqkv + 20971520u; off = u - 2621440; }
  const float4* s4 = (const float4*)sp + off * 2;
  float4 a = s4[0], b = s4[1];
  bf16x8 o = { (bf16)a.x, (bf16)a.y, (bf16)a.z, (bf16)a.w,
               (bf16)b.x, (bf16)b.y, (bf16)b.z, (bf16)b.w };
  *(bf16x8*)(dp + off * 8) = o;
}

// ---------------- 256^2 single-barrier 8-phase GEMM (r10 best) -----------
template <typename OutT>
__global__ __launch_bounds__(512, 2) void k_gemmCS(
    const bf16* __restrict__ A, const bf16* __restrict__ Bw,
    OutT* __restrict__ C, int K, int N, int nbx) {
  __shared__ __align__(16) bf16 lds[2][4][8192];  // 128 KiB
  const int tid = threadIdx.x;
  const int lane = tid & 63;
  const int w = tid >> 6;
  const int wm = w >> 2, wn = w & 3;  // 2M x 4N, wave out 128x64
  const int l16 = lane & 15, lh = lane >> 4;

  const int cpx = gridDim.x >> 3;
  const int swz = (blockIdx.x & 7) * cpx + (blockIdx.x >> 3);
  const int by = swz / nbx, bx = swz % nbx;
  const size_t m0 = (size_t)by * 256, n0 = (size_t)bx * 256;

  const int row0 = tid >> 2;
  const int cOff = ((tid & 3) ^ ((row0 >> 1) & 3)) * 8;
  const bf16* pA0 = A + (m0 + row0) * K + cOff;
  const bf16* pA1 = pA0 + (size_t)128 * K;
  const bf16* pB0 = Bw + (n0 + row0) * K + cOff;
  const bf16* pB1 = pB0 + (size_t)128 * K;

#define SA(s, h, t)                                        \
  { const int kk = (t) * 64 + (h) * 32;                    \
    async16(pA0 + kk, &lds[s][h][0] + tid * 8);            \
    async16(pA1 + kk, &lds[s][h][0] + 4096 + tid * 8); }
#define SB(s, h, t)                                        \
  { const int kk = (t) * 64 + (h) * 32;                    \
    async16(pB0 + kk, &lds[s][2 + (h)][0] + tid * 8);      \
    async16(pB1 + kk, &lds[s][2 + (h)][0] + 4096 + tid * 8); }

#define RDA(s, u, mh)                                                 \
  UNROLL for (int x = 0; x < 4; ++x) {                                \
    int p = (wm * 128 + (mh) * 64 + x * 16 + l16) * 64 + lh * 16;     \
    p ^= ((p >> 7) & 3) << 4;                                         \
    Ar[x] = *(const bf16x8*)((const char*)&lds[s][u][0] + p);         \
  }
#define RDB(s, u)                                                     \
  UNROLL for (int y = 0; y < 4; ++y) {                                \
    int p = (wn * 64 + y * 16 + l16) * 64 + lh * 16;                  \
    p ^= ((p >> 7) & 3) << 4;                                         \
    Br[y] = *(const bf16x8*)((const char*)&lds[s][u][0] + p);         \
  }
#define MF(mh)                                                        \
  { __builtin_amdgcn_s_setprio(1);                                    \
    UNROLL for (int x = 0; x < 4; ++x)                                \
      UNROLL for (int y = 0; y < 4; ++y)                              \
        acc[(mh) * 4 + x][y] = __builtin_amdgcn_mfma_f32_16x16x32_bf16( \
            Ar[x], Br[y], acc[(mh) * 4 + x][y], 0, 0, 0);             \
    __builtin_amdgcn_s_setprio(0); }

  f32x4 acc[8][4] = {};
  const int NITER = K >> 7;

  SA(0, 0, 0); SB(0, 0, 0); SA(0, 1, 0); SB(0, 1, 0); SA(1, 0, 1); SB(1, 0, 1);
  VMCNT(8);

#define ITER_BODY(i, LAST)                                                  \
  { const int t0 = 2 * (i), t1 = t0 + 1;                                    \
    bf16x8 Ar[4], Br[4];                                                    \
    BARR; RDA(0, 0, 0); RDB(0, 2); SA(1, 1, t1); MF(0);                     \
    BARR; RDA(0, 0, 1); SB(1, 1, t1); MF(1); VMCNT(8);                      \
    BARR; RDA(0, 1, 0); RDB(0, 3); if (!(LAST)) SA(0, 0, t0 + 2); MF(0);    \
    BARR; RDA(0, 1, 1); if (!(LAST)) SB(0, 0, t0 + 2); MF(1);               \
    if (LAST) { VMCNT(4); } else { VMCNT(8); }                              \
    BARR; RDA(1, 0, 0); RDB(1, 2); if (!(LAST)) SA(0, 1, t0 + 2); MF(0);    \
    BARR; RDA(1, 0, 1); if (!(LAST)) SB(0, 1, t0 + 2); MF(1);               \
    if (LAST) { VMCNT(0); } else { VMCNT(8); }                              \
    BARR; RDA(1, 1, 0); RDB(1, 3); if (!(LAST)) SA(1, 0, t1 + 2); MF(0);    \
    BARR; RDA(1, 1, 1); if (!(LAST)) SB(1, 0, t1 + 2); MF(1);               \
    if (!(LAST)) VMCNT(8); }

  for (int i = 0; i < NITER - 1; ++i) ITER_BODY(i, 0);
  ITER_BODY(NITER - 1, 1);

  UNROLL for (int mi = 0; mi < 8; ++mi) {
    size_t row = m0 + wm * 128 + mi * 16 + lh * 4;
    UNROLL for (int ni = 0; ni < 4; ++ni) {
      size_t col = n0 + wn * 64 + ni * 16 + l16;
      UNROLL for (int j = 0; j < 4; ++j)
        C[(row + j) * N + col] = (OutT)acc[mi][ni][j];
    }
  }
#undef SA
#undef SB
#undef RDA
#undef RDB
#undef MF
#undef ITER_BODY
}

// ---------------- RoPE + scatter (Q,K; V handled by k_vtrans) ------------
__global__ void k_rope(const bf16* __restrict__ QKV, bf16* __restrict__ Qr,
                       bf16* __restrict__ Kr) {
  int gid = blockIdx.x * 256 + threadIdx.x;
  int p = gid & 63;
  int rest = gid >> 6;
  int slot = rest % 40;
  int tok = rest / 40;
  int s = tok & 2047;
  int b = tok >> 11;
  const bf16* src = QKV + (size_t)tok * 6144 + slot * 128;
  float x1 = (float)src[p], x2 = (float)src[p + 64];
  float f = exp2f((float)p * (-13.287712379549449f / 64.0f));
  float sn, cn;
  sincosf((float)s * f, &sn, &cn);
  float o1 = x1 * cn - x2 * sn;
  float o2 = x2 * cn + x1 * sn;
  bf16* dst;
  if (slot < 32) {
    o1 *= 0.08838834764831845f;
    o2 *= 0.08838834764831845f;
    dst = Qr + (((size_t)b * 32 + slot) * 2048 + s) * 128;
  } else {
    dst = Kr + (((size_t)b * 8 + (slot - 32)) * 2048 + s) * 128;
  }
  dst[p] = (bf16)o1;
  dst[p + 64] = (bf16)o2;
}

// ---------------- V transpose: QKV[tok][5120+hkv*128+d] -> Vtg[b][hkv][d][s]
__global__ void k_vtrans(const bf16* __restrict__ QKV, bf16* __restrict__ Vtg) {
  __shared__ __align__(16) bf16 T[64 * 64];
  const int tid = threadIdx.x;
  const int dt = blockIdx.x & 1;
  const int st = (blockIdx.x >> 1) & 31;
  const int hh = blockIdx.x >> 6;
  const int hkv = hh & 7, b = hh >> 3;
  const int s0 = st * 64, d0 = dt * 64;
  const bf16* src = QKV + (size_t)(b * 2048 + s0) * 6144 + 5120 + hkv * 128 + d0;
  UNROLL for (int k = 0; k < 2; ++k) {
    int cc = tid * 2 + k;
    int r = cc >> 3, c8 = cc & 7;
    bf16x8 v = *(const bf16x8*)(src + (size_t)r * 6144 + c8 * 8);
    int byte = (r * 128 + c8 * 16) ^ ((r & 7) << 4);
    *(bf16x8*)((char*)T + byte) = v;
  }
  __syncthreads();
  bf16* dst = Vtg + ((size_t)(b * 8 + hkv) * 128 + d0) * 2048 + s0;
  UNROLL for (int k = 0; k < 2; ++k) {
    int cc = tid * 2 + k;
    int d = cc >> 3, s8 = cc & 7;
    bf16x8 v;
    UNROLL for (int j = 0; j < 8; ++j) {
      int s = s8 * 8 + j;
      int byte = (s * 128 + d * 2) ^ ((s & 7) << 4);
      v[j] = *(const bf16*)((const char*)T + byte);
    }
    *(bf16x8*)(dst + (size_t)d * 2048 + s8 * 8) = v;
  }
}

// ---------------- flash attention (causal, GQA 4:1) ----------------------
// r5 structure (KVBLK=64, proven swizzles) but SINGLE-buffered K/V:
// LDS = K 16K + V 16K + P 16K = 48 KiB -> 3 blocks/CU (12 waves).
// Per tile: stage -> vmcnt(0) -> barrier -> compute -> barrier. The stage
// drain is covered by the other 2 blocks' compute (TLP, m114), and K/V
// tiles are L2-hot (shared by 4 heads x 16 blocks per (b,hkv)).
__global__ __launch_bounds__(256, 3) void k_flash(
    const bf16* __restrict__ Qr, const bf16* __restrict__ Kr,
    const bf16* __restrict__ Vtg, bf16* __restrict__ Out) {
  __shared__ __align__(16) bf16 Kl[64 * 128];
  __shared__ __align__(16) bf16 Vl[128 * 64];
  __shared__ __align__(16) bf16 Pl[4][32 * 64];
  const int tid = threadIdx.x;
  const int lane = tid & 63;
  const int w = tid >> 6;
  const int l16 = lane & 15, lh = lane >> 4;
  const int pid = blockIdx.x & 7;
  const int hl = blockIdx.x >> 3;
  const int h = hl & 31, b = hl >> 5;
  const int hkv = h >> 2;
  const bf16* Kbase = Kr + ((size_t)(b * 8 + hkv)) * 2048 * 128;
  const bf16* Vbase = Vtg + ((size_t)(b * 8 + hkv)) * 128 * 2048;
  bf16* P = &Pl[w][0];

  int kOff[4], vOff[4], ldsOff[4];
  UNROLL for (int i = 0; i < 4; ++i) {
    int c = (w * 4 + i) * 64 + lane;
    ldsOff[i] = c * 8;
    int r = c >> 4, p = c & 15;
    kOff[i] = r * 128 + (p ^ (r & 7)) * 8;
    int r2 = c >> 3, p2 = c & 7;
    vOff[i] = r2 * 2048 + (p2 ^ (r2 & 7)) * 8;
  }

  for (int qi = 0; qi < 2; ++qi) {
    const int q = qi ? (15 - pid) : pid;
    const int q0 = q * 128;
    const int nt = 2 * q + 2;

    bf16x8 qf[2][4];
    UNROLL for (int m = 0; m < 2; ++m) {
      const bf16* qb = Qr + (((size_t)(b * 32 + h)) * 2048 + q0 + w * 32 + m * 16 + l16) * 128 + lh * 8;
      UNROLL for (int kc = 0; kc < 4; ++kc) qf[m][kc] = *(const bf16x8*)(qb + kc * 32);
    }
    f32x4 acc[2][8] = {};
    float mrow[2][4] = {{-1e30f, -1e30f, -1e30f, -1e30f}, {-1e30f, -1e30f, -1e30f, -1e30f}};
    float lrow[2][4] = {};

    for (int t = 0; t < nt; ++t) {
      // stage tile t (single buffer)
      UNROLL for (int i = 0; i < 4; ++i) {
        async16(Kbase + (size_t)t * 8192 + kOff[i], &Kl[0] + ldsOff[i]);
        async16(Vbase + (size_t)t * 64 + vOff[i], &Vl[0] + ldsOff[i]);
      }
      VMCNT(0);
      BARR;  // tile visible to all waves

      f32x4 sf[2][4] = {};
      UNROLL for (int ni = 0; ni < 4; ++ni) {
        int row = ni * 16 + l16;
        bf16x8 kf[4];
        UNROLL for (int kc = 0; kc < 4; ++kc) {
          int byte = (row * 256 + kc * 64 + lh * 16) ^ ((row & 7) << 4);
          kf[kc] = *(const bf16x8*)((const char*)&Kl[0] + byte);
        }
        UNROLL for (int m = 0; m < 2; ++m)
          UNROLL for (int kc = 0; kc < 4; ++kc)
            sf[m][ni] = __builtin_amdgcn_mfma_f32_16x16x32_bf16(qf[m][kc], kf[kc], sf[m][ni], 0, 0, 0);
      }
      if (t >= 2 * q) {
        UNROLL for (int m = 0; m < 2; ++m)
          UNROLL for (int ni = 0; ni < 4; ++ni) {
            int key = t * 64 + ni * 16 + l16;
            UNROLL for (int j = 0; j < 4; ++j) {
              int rowg = q0 + w * 32 + m * 16 + lh * 4 + j;
              if (key > rowg) sf[m][ni][j] = -1e30f;
            }
          }
      }
      float corr[2][4];
      UNROLL for (int m = 0; m < 2; ++m)
        UNROLL for (int j = 0; j < 4; ++j) {
          float mx = fmaxf(fmaxf(sf[m][0][j], sf[m][1][j]), fmaxf(sf[m][2][j], sf[m][3][j]));
          mx = fmaxf(mx, __shfl_xor(mx, 1));
          mx = fmaxf(mx, __shfl_xor(mx, 2));
          mx = fmaxf(mx, __shfl_xor(mx, 4));
          mx = fmaxf(mx, __shfl_xor(mx, 8));
          float mn = fmaxf(mrow[m][j], mx);
          corr[m][j] = __expf(mrow[m][j] - mn);
          mrow[m][j] = mn;
          float rs = 0.f;
          UNROLL for (int ni = 0; ni < 4; ++ni) {
            float pv = __expf(sf[m][ni][j] - mn);
            sf[m][ni][j] = pv;
            rs += pv;
          }
          rs += __shfl_xor(rs, 1);
          rs += __shfl_xor(rs, 2);
          rs += __shfl_xor(rs, 4);
          rs += __shfl_xor(rs, 8);
          lrow[m][j] = lrow[m][j] * corr[m][j] + rs;
        }
      UNROLL for (int m = 0; m < 2; ++m)
        UNROLL for (int di = 0; di < 8; ++di)
          UNROLL for (int j = 0; j < 4; ++j) acc[m][di][j] *= corr[m][j];
      UNROLL for (int m = 0; m < 2; ++m)
        UNROLL for (int ni = 0; ni < 4; ++ni)
          UNROLL for (int j = 0; j < 4; ++j) {
            int row = m * 16 + lh * 4 + j;
            int byte = (row * 128 + ni * 32 + l16 * 2) ^ ((row & 7) << 4);
            *(bf16*)((char*)P + byte) = (bf16)sf[m][ni][j];
          }
      UNROLL for (int kc = 0; kc < 2; ++kc) {
        bf16x8 pa[2];
        UNROLL for (int m = 0; m < 2; ++m) {
          int row = m * 16 + l16;
          int byte = (row * 128 + kc * 64 + lh * 16) ^ ((row & 7) << 4);
          pa[m] = *(const bf16x8*)((const char*)P + byte);
        }
        UNROLL for (int di = 0; di < 8; ++di) {
          int d = di * 16 + l16;
          int byte = (d * 128 + kc * 64 + lh * 16) ^ ((d & 7) << 4);
          bf16x8 vb = *(const bf16x8*)((const char*)&Vl[0] + byte);
          UNROLL for (int m = 0; m < 2; ++m)
            acc[m][di] = __builtin_amdgcn_mfma_f32_16x16x32_bf16(pa[m], vb, acc[m][di], 0, 0, 0);
        }
      }
      BARR;  // all reads of Kl/Vl done before next stage overwrites
    }

    UNROLL for (int m = 0; m < 2; ++m)
      UNROLL for (int j = 0; j < 4; ++j) {
        float inv = 1.0f / lrow[m][j];
        int rowg = q0 + w * 32 + m * 16 + lh * 4 + j;
        bf16* ob = Out + ((size_t)(b * 2048) + rowg) * 4096 + h * 128 + l16;
        UNROLL for (int di = 0; di < 8; ++di)
          ob[di * 16] = (bf16)(acc[m][di][j] * inv);
      }
  }
}

// ---------------- launch ----------------
extern "C" void kernel_launch(void* const* d_in, const int* in_sizes, int n_in,
                              void* d_out, int out_size, void* d_ws, size_t ws_size,
                              hipStream_t stream) {
  const float* hidden = (const float*)d_in[0];
  const float* Wq = (const float*)d_in[3];
  const float* Wk = (const float*)d_in[4];
  const float* Wv = (const float*)d_in[5];
  const float* Wo = (const float*)d_in[6];
  float* out = (float*)d_out;

  // workspace layout (bytes):
  //   Xb   [4096*4096] bf16 @ 0        (reused as AttnOut)
  //   Wqkv [6144*4096] bf16 @ 32M      (reused as Wo_bf16 after gemm1)
  //   QKV  [4096*6144] bf16 @ 80M
  //   Qr   [2,32,2048,128] bf16 @ 128M
  //   Kr   [2,8,2048,128]  bf16 @ 160M
  //   Vtg  [2,8,128,2048]  bf16 @ 168M   total 176 MiB
  char* ws = (char*)d_ws;
  if (ws_size < 184549376u) return;
  bf16* Xb = (bf16*)(ws);
  bf16* Wqkv = (bf16*)(ws + 33554432u);
  bf16* QKV = (bf16*)(ws + 83886080u);
  bf16* Qr = (bf16*)(ws + 134217728u);
  bf16* Kr = (bf16*)(ws + 167772160u);
  bf16* Vtg = (bf16*)(ws + 176160768u);
  bf16* AttnO = Xb;
  bf16* Wob = Wqkv;

  k_cvt<<<8192, 256, 0, stream>>>(hidden, Xb, 2097152);
  k_cvtw3<<<12288, 256, 0, stream>>>(Wq, Wk, Wv, Wqkv);
  // QKV GEMM: 16 x 24 = 384 blocks (256^2 tiles, compiler-scheduled phases)
  k_gemmCS<bf16><<<384, 512, 0, stream>>>(Xb, Wqkv, QKV, 4096, 6144, 24);
  k_rope<<<40960, 256, 0, stream>>>(QKV, Qr, Kr);
  k_vtrans<<<1024, 256, 0, stream>>>(QKV, Vtg);
  k_cvt<<<8192, 256, 0, stream>>>(Wo, Wob, 2097152);
  k_flash<<<512, 256, 0, stream>>>(Qr, Kr, Vtg, AttnO);
  // O-proj: 16 x 16 = 256 blocks (one dispatch wave)
  k_gemmCS<float><<<256, 512, 0, stream>>>(AttnO, Wob, out, 4096, 4096, 16);
}

// Round 13
// 574.353 us; speedup vs baseline: 2.0298x; 2.0298x over previous
//
#include <hip/hip_runtime.h>
#include <hip/hip_bf16.h>

// Llama attention block: B=2, S=2048, H=4096, NH=32, NKV=8, HD=128, GQA 4:1.
// Pipeline (bf16 MFMA, fp32 accumulate):
//   1. convert hidden -> bf16; Wq/Wk/Wv -> bf16 in one dispatch
//   2. QKV = X @ Wqkv^T  (256^2 8-phase GEMM, compiler-scheduled — r10 best)
//   3. RoPE (Q,K) + scatter, bf16x8-vectorized; fold 1/sqrt(128) into Q
//   4. V transpose: QKV -> Vtg [b][hkv][128 d][2048 s]
//   5. flash attention (causal): KVBLK=64, double-buffered LDS (r5 proven)
//   6. out = AttnOut @ Wo^T (fp32), same GEMM

typedef __bf16 bf16;
typedef __bf16 bf16x8 __attribute__((ext_vector_type(8)));
typedef float f32x4 __attribute__((ext_vector_type(4)));

#define UNROLL _Pragma("unroll")

__device__ __forceinline__ void async16(const bf16* g, bf16* l) {
  __builtin_amdgcn_global_load_lds(
      (const __attribute__((address_space(1))) void*)g,
      (__attribute__((address_space(3))) void*)l,
      16, 0, 0);
}

#define BARR { __builtin_amdgcn_s_barrier(); }
#define VMCNT(n) { asm volatile("s_waitcnt vmcnt(" #n ")" ::: "memory"); }

// ---------------- fp32 -> bf16 convert (8 elem/thread) ----------------
__global__ void k_cvt(const float* __restrict__ s, bf16* __restrict__ d, int n8) {
  int i = blockIdx.x * 256 + threadIdx.x;
  if (i >= n8) return;
  const float4* sp = (const float4*)s + (size_t)i * 2;
  float4 a = sp[0], b = sp[1];
  bf16x8 o = { (bf16)a.x, (bf16)a.y, (bf16)a.z, (bf16)a.w,
               (bf16)b.x, (bf16)b.y, (bf16)b.z, (bf16)b.w };
  *(bf16x8*)(d + (size_t)i * 8) = o;
}

// ---------------- Wq/Wk/Wv converts in one dispatch ----------------------
__global__ void k_cvtw3(const float* __restrict__ Wq, const float* __restrict__ Wk,
                        const float* __restrict__ Wv, bf16* __restrict__ Wqkv) {
  int u = blockIdx.x * 256 + threadIdx.x;
  const float* sp;
  bf16* dp;
  size_t off;
  if (u < 2097152) { sp = Wq; dp = Wqkv; off = u; }
  else if (u < 2621440) { sp = Wk; dp = Wqkv + 16777216u; off = u - 2097152; }
  else { sp = Wv; dp = Wqkv + 20971520u; off = u - 2621440; }
  const float4* s4 = (const float4*)sp + off * 2;
  float4 a = s4[0], b = s4[1];
  bf16x8 o = { (bf16)a.x, (bf16)a.y, (bf16)a.z, (bf16)a.w,
               (bf16)b.x, (bf16)b.y, (bf16)b.z, (bf16)b.w };
  *(bf16x8*)(dp + off * 8) = o;
}

// ---------------- 256^2 single-barrier 8-phase GEMM (r10 best) -----------
template <typename OutT>
__global__ __launch_bounds__(512, 2) void k_gemmCS(
    const bf16* __restrict__ A, const bf16* __restrict__ Bw,
    OutT* __restrict__ C, int K, int N, int nbx) {
  __shared__ __align__(16) bf16 lds[2][4][8192];  // 128 KiB
  const int tid = threadIdx.x;
  const int lane = tid & 63;
  const int w = tid >> 6;
  const int wm = w >> 2, wn = w & 3;  // 2M x 4N, wave out 128x64
  const int l16 = lane & 15, lh = lane >> 4;

  const int cpx = gridDim.x >> 3;
  const int swz = (blockIdx.x & 7) * cpx + (blockIdx.x >> 3);
  const int by = swz / nbx, bx = swz % nbx;
  const size_t m0 = (size_t)by * 256, n0 = (size_t)bx * 256;

  const int row0 = tid >> 2;
  const int cOff = ((tid & 3) ^ ((row0 >> 1) & 3)) * 8;
  const bf16* pA0 = A + (m0 + row0) * K + cOff;
  const bf16* pA1 = pA0 + (size_t)128 * K;
  const bf16* pB0 = Bw + (n0 + row0) * K + cOff;
  const bf16* pB1 = pB0 + (size_t)128 * K;

#define SA(s, h, t)                                        \
  { const int kk = (t) * 64 + (h) * 32;                    \
    async16(pA0 + kk, &lds[s][h][0] + tid * 8);            \
    async16(pA1 + kk, &lds[s][h][0] + 4096 + tid * 8); }
#define SB(s, h, t)                                        \
  { const int kk = (t) * 64 + (h) * 32;                    \
    async16(pB0 + kk, &lds[s][2 + (h)][0] + tid * 8);      \
    async16(pB1 + kk, &lds[s][2 + (h)][0] + 4096 + tid * 8); }

#define RDA(s, u, mh)                                                 \
  UNROLL for (int x = 0; x < 4; ++x) {                                \
    int p = (wm * 128 + (mh) * 64 + x * 16 + l16) * 64 + lh * 16;     \
    p ^= ((p >> 7) & 3) << 4;                                         \
    Ar[x] = *(const bf16x8*)((const char*)&lds[s][u][0] + p);         \
  }
#define RDB(s, u)                                                     \
  UNROLL for (int y = 0; y < 4; ++y) {                                \
    int p = (wn * 64 + y * 16 + l16) * 64 + lh * 16;                  \
    p ^= ((p >> 7) & 3) << 4;                                         \
    Br[y] = *(const bf16x8*)((const char*)&lds[s][u][0] + p);         \
  }
#define MF(mh)                                                        \
  { __builtin_amdgcn_s_setprio(1);                                    \
    UNROLL for (int x = 0; x < 4; ++x)                                \
      UNROLL for (int y = 0; y < 4; ++y)                              \
        acc[(mh) * 4 + x][y] = __builtin_amdgcn_mfma_f32_16x16x32_bf16( \
            Ar[x], Br[y], acc[(mh) * 4 + x][y], 0, 0, 0);             \
    __builtin_amdgcn_s_setprio(0); }

  f32x4 acc[8][4] = {};
  const int NITER = K >> 7;

  SA(0, 0, 0); SB(0, 0, 0); SA(0, 1, 0); SB(0, 1, 0); SA(1, 0, 1); SB(1, 0, 1);
  VMCNT(8);

#define ITER_BODY(i, LAST)                                                  \
  { const int t0 = 2 * (i), t1 = t0 + 1;                                    \
    bf16x8 Ar[4], Br[4];                                                    \
    BARR; RDA(0, 0, 0); RDB(0, 2); SA(1, 1, t1); MF(0);                     \
    BARR; RDA(0, 0, 1); SB(1, 1, t1); MF(1); VMCNT(8);                      \
    BARR; RDA(0, 1, 0); RDB(0, 3); if (!(LAST)) SA(0, 0, t0 + 2); MF(0);    \
    BARR; RDA(0, 1, 1); if (!(LAST)) SB(0, 0, t0 + 2); MF(1);               \
    if (LAST) { VMCNT(4); } else { VMCNT(8); }                              \
    BARR; RDA(1, 0, 0); RDB(1, 2); if (!(LAST)) SA(0, 1, t0 + 2); MF(0);    \
    BARR; RDA(1, 0, 1); if (!(LAST)) SB(0, 1, t0 + 2); MF(1);               \
    if (LAST) { VMCNT(0); } else { VMCNT(8); }                              \
    BARR; RDA(1, 1, 0); RDB(1, 3); if (!(LAST)) SA(1, 0, t1 + 2); MF(0);    \
    BARR; RDA(1, 1, 1); if (!(LAST)) SB(1, 0, t1 + 2); MF(1);               \
    if (!(LAST)) VMCNT(8); }

  for (int i = 0; i < NITER - 1; ++i) ITER_BODY(i, 0);
  ITER_BODY(NITER - 1, 1);

  UNROLL for (int mi = 0; mi < 8; ++mi) {
    size_t row = m0 + wm * 128 + mi * 16 + lh * 4;
    UNROLL for (int ni = 0; ni < 4; ++ni) {
      size_t col = n0 + wn * 64 + ni * 16 + l16;
      UNROLL for (int j = 0; j < 4; ++j)
        C[(row + j) * N + col] = (OutT)acc[mi][ni][j];
    }
  }
#undef SA
#undef SB
#undef RDA
#undef RDB
#undef MF
#undef ITER_BODY
}

// ---------------- RoPE + scatter (Q,K), bf16x8-vectorized ----------------
// thread = (tok, slot 0..39, seg 0..7); handles pairs p = seg*8 .. seg*8+7
// (p pairs with p+64). 16B loads/stores on both halves.
__global__ void k_rope(const bf16* __restrict__ QKV, bf16* __restrict__ Qr,
                       bf16* __restrict__ Kr) {
  int gid = blockIdx.x * 256 + threadIdx.x;  // < 1310720
  int seg = gid & 7;
  int rest = gid >> 3;
  int slot = rest % 40;
  int tok = rest / 40;
  int s = tok & 2047;
  int b = tok >> 11;
  const bf16* src = QKV + (size_t)tok * 6144 + slot * 128 + seg * 8;
  bf16x8 a = *(const bf16x8*)src;
  bf16x8 c = *(const bf16x8*)(src + 64);
  bf16x8 o1v, o2v;
  const float scale = (slot < 32) ? 0.08838834764831845f : 1.0f;
  UNROLL for (int j = 0; j < 8; ++j) {
    int p = seg * 8 + j;
    float f = exp2f((float)p * (-13.287712379549449f / 64.0f));
    float sn, cn;
    sincosf((float)s * f, &sn, &cn);
    float x1 = (float)a[j], x2 = (float)c[j];
    o1v[j] = (bf16)((x1 * cn - x2 * sn) * scale);
    o2v[j] = (bf16)((x2 * cn + x1 * sn) * scale);
  }
  bf16* dst;
  if (slot < 32) {
    dst = Qr + (((size_t)b * 32 + slot) * 2048 + s) * 128 + seg * 8;
  } else {
    dst = Kr + (((size_t)b * 8 + (slot - 32)) * 2048 + s) * 128 + seg * 8;
  }
  *(bf16x8*)dst = o1v;
  *(bf16x8*)(dst + 64) = o2v;
}

// ---------------- V transpose: QKV[tok][5120+hkv*128+d] -> Vtg[b][hkv][d][s]
__global__ void k_vtrans(const bf16* __restrict__ QKV, bf16* __restrict__ Vtg) {
  __shared__ __align__(16) bf16 T[64 * 64];
  const int tid = threadIdx.x;
  const int dt = blockIdx.x & 1;
  const int st = (blockIdx.x >> 1) & 31;
  const int hh = blockIdx.x >> 6;
  const int hkv = hh & 7, b = hh >> 3;
  const int s0 = st * 64, d0 = dt * 64;
  const bf16* src = QKV + (size_t)(b * 2048 + s0) * 6144 + 5120 + hkv * 128 + d0;
  UNROLL for (int k = 0; k < 2; ++k) {
    int cc = tid * 2 + k;
    int r = cc >> 3, c8 = cc & 7;
    bf16x8 v = *(const bf16x8*)(src + (size_t)r * 6144 + c8 * 8);
    int byte = (r * 128 + c8 * 16) ^ ((r & 7) << 4);
    *(bf16x8*)((char*)T + byte) = v;
  }
  __syncthreads();
  bf16* dst = Vtg + ((size_t)(b * 8 + hkv) * 128 + d0) * 2048 + s0;
  UNROLL for (int k = 0; k < 2; ++k) {
    int cc = tid * 2 + k;
    int d = cc >> 3, s8 = cc & 7;
    bf16x8 v;
    UNROLL for (int j = 0; j < 8; ++j) {
      int s = s8 * 8 + j;
      int byte = (s * 128 + d * 2) ^ ((s & 7) << 4);
      v[j] = *(const bf16*)((const char*)T + byte);
    }
    *(bf16x8*)(dst + (size_t)d * 2048 + s8 * 8) = v;
  }
}

// ---------------- flash attention (causal, GQA 4:1) — r5 proven version --
__global__ __launch_bounds__(256, 2) void k_flash(
    const bf16* __restrict__ Qr, const bf16* __restrict__ Kr,
    const bf16* __restrict__ Vtg, bf16* __restrict__ Out) {
  __shared__ __align__(16) bf16 Kl[2][64 * 128];
  __shared__ __align__(16) bf16 Vl[2][128 * 64];
  __shared__ __align__(16) bf16 Pl[4][32 * 64];
  const int tid = threadIdx.x;
  const int lane = tid & 63;
  const int w = tid >> 6;
  const int l16 = lane & 15, lh = lane >> 4;
  const int pid = blockIdx.x & 7;
  const int hl = blockIdx.x >> 3;
  const int h = hl & 31, b = hl >> 5;
  const int hkv = h >> 2;
  const bf16* Kbase = Kr + ((size_t)(b * 8 + hkv)) * 2048 * 128;
  const bf16* Vbase = Vtg + ((size_t)(b * 8 + hkv)) * 128 * 2048;
  bf16* P = &Pl[w][0];

  int kOff[4], vOff[4], ldsOff[4];
  UNROLL for (int i = 0; i < 4; ++i) {
    int c = (w * 4 + i) * 64 + lane;
    ldsOff[i] = c * 8;
    int r = c >> 4, p = c & 15;
    kOff[i] = r * 128 + (p ^ (r & 7)) * 8;
    int r2 = c >> 3, p2 = c & 7;
    vOff[i] = r2 * 2048 + (p2 ^ (r2 & 7)) * 8;
  }

  for (int qi = 0; qi < 2; ++qi) {
    const int q = qi ? (15 - pid) : pid;
    const int q0 = q * 128;
    const int nt = 2 * q + 2;

    bf16x8 qf[2][4];
    UNROLL for (int m = 0; m < 2; ++m) {
      const bf16* qb = Qr + (((size_t)(b * 32 + h)) * 2048 + q0 + w * 32 + m * 16 + l16) * 128 + lh * 8;
      UNROLL for (int kc = 0; kc < 4; ++kc) qf[m][kc] = *(const bf16x8*)(qb + kc * 32);
    }
    f32x4 acc[2][8] = {};
    float mrow[2][4] = {{-1e30f, -1e30f, -1e30f, -1e30f}, {-1e30f, -1e30f, -1e30f, -1e30f}};
    float lrow[2][4] = {};

    UNROLL for (int i = 0; i < 4; ++i) {
      async16(Kbase + kOff[i], &Kl[0][0] + ldsOff[i]);
      async16(Vbase + vOff[i], &Vl[0][0] + ldsOff[i]);
    }
    __syncthreads();

    for (int t = 0; t < nt; ++t) {
      const int cur = t & 1;
      if (t + 1 < nt) {
        const int nb = t + 1;
        UNROLL for (int i = 0; i < 4; ++i) {
          async16(Kbase + (size_t)nb * 8192 + kOff[i], &Kl[cur ^ 1][0] + ldsOff[i]);
          async16(Vbase + (size_t)nb * 64 + vOff[i], &Vl[cur ^ 1][0] + ldsOff[i]);
        }
      }
      f32x4 sf[2][4] = {};
      UNROLL for (int ni = 0; ni < 4; ++ni) {
        int row = ni * 16 + l16;
        bf16x8 kf[4];
        UNROLL for (int kc = 0; kc < 4; ++kc) {
          int byte = (row * 256 + kc * 64 + lh * 16) ^ ((row & 7) << 4);
          kf[kc] = *(const bf16x8*)((const char*)&Kl[cur][0] + byte);
        }
        UNROLL for (int m = 0; m < 2; ++m)
          UNROLL for (int kc = 0; kc < 4; ++kc)
            sf[m][ni] = __builtin_amdgcn_mfma_f32_16x16x32_bf16(qf[m][kc], kf[kc], sf[m][ni], 0, 0, 0);
      }
      if (t >= 2 * q) {
        UNROLL for (int m = 0; m < 2; ++m)
          UNROLL for (int ni = 0; ni < 4; ++ni) {
            int key = t * 64 + ni * 16 + l16;
            UNROLL for (int j = 0; j < 4; ++j) {
              int rowg = q0 + w * 32 + m * 16 + lh * 4 + j;
              if (key > rowg) sf[m][ni][j] = -1e30f;
            }
          }
      }
      float corr[2][4];
      UNROLL for (int m = 0; m < 2; ++m)
        UNROLL for (int j = 0; j < 4; ++j) {
          float mx = fmaxf(fmaxf(sf[m][0][j], sf[m][1][j]), fmaxf(sf[m][2][j], sf[m][3][j]));
          mx = fmaxf(mx, __shfl_xor(mx, 1));
          mx = fmaxf(mx, __shfl_xor(mx, 2));
          mx = fmaxf(mx, __shfl_xor(mx, 4));
          mx = fmaxf(mx, __shfl_xor(mx, 8));
          float mn = fmaxf(mrow[m][j], mx);
          corr[m][j] = __expf(mrow[m][j] - mn);
          mrow[m][j] = mn;
          float rs = 0.f;
          UNROLL for (int ni = 0; ni < 4; ++ni) {
            float pv = __expf(sf[m][ni][j] - mn);
            sf[m][ni][j] = pv;
            rs += pv;
          }
          rs += __shfl_xor(rs, 1);
          rs += __shfl_xor(rs, 2);
          rs += __shfl_xor(rs, 4);
          rs += __shfl_xor(rs, 8);
          lrow[m][j] = lrow[m][j] * corr[m][j] + rs;
        }
      UNROLL for (int m = 0; m < 2; ++m)
        UNROLL for (int di = 0; di < 8; ++di)
          UNROLL for (int j = 0; j < 4; ++j) acc[m][di][j] *= corr[m][j];
      UNROLL for (int m = 0; m < 2; ++m)
        UNROLL for (int ni = 0; ni < 4; ++ni)
          UNROLL for (int j = 0; j < 4; ++j) {
            int row = m * 16 + lh * 4 + j;
            int byte = (row * 128 + ni * 32 + l16 * 2) ^ ((row & 7) << 4);
            *(bf16*)((char*)P + byte) = (bf16)sf[m][ni][j];
          }
      UNROLL for (int kc = 0; kc < 2; ++kc) {
        bf16x8 pa[2];
        UNROLL for (int m = 0; m < 2; ++m) {
          int row = m * 16 + l16;
          int byte = (row * 128 + kc * 64 + lh * 16) ^ ((row & 7) << 4);
          pa[m] = *(const bf16x8*)((const char*)P + byte);
        }
        UNROLL for (int di = 0; di < 8; ++di) {
          int d = di * 16 + l16;
          int byte = (d * 128 + kc * 64 + lh * 16) ^ ((d & 7) << 4);
          bf16x8 vb = *(const bf16x8*)((const char*)&Vl[cur][0] + byte);
          UNROLL for (int m = 0; m < 2; ++m)
            acc[m][di] = __builtin_amdgcn_mfma_f32_16x16x32_bf16(pa[m], vb, acc[m][di], 0, 0, 0);
        }
      }
      __syncthreads();
    }

    UNROLL for (int m = 0; m < 2; ++m)
      UNROLL for (int j = 0; j < 4; ++j) {
        float inv = 1.0f / lrow[m][j];
        int rowg = q0 + w * 32 + m * 16 + lh * 4 + j;
        bf16* ob = Out + ((size_t)(b * 2048) + rowg) * 4096 + h * 128 + l16;
        UNROLL for (int di = 0; di < 8; ++di)
          ob[di * 16] = (bf16)(acc[m][di][j] * inv);
      }
  }
}

// ---------------- launch ----------------
extern "C" void kernel_launch(void* const* d_in, const int* in_sizes, int n_in,
                              void* d_out, int out_size, void* d_ws, size_t ws_size,
                              hipStream_t stream) {
  const float* hidden = (const float*)d_in[0];
  const float* Wq = (const float*)d_in[3];
  const float* Wk = (const float*)d_in[4];
  const float* Wv = (const float*)d_in[5];
  const float* Wo = (const float*)d_in[6];
  float* out = (float*)d_out;

  // workspace layout (bytes):
  //   Xb   [4096*4096] bf16 @ 0        (reused as AttnOut)
  //   Wqkv [6144*4096] bf16 @ 32M      (reused as Wo_bf16 after gemm1)
  //   QKV  [4096*6144] bf16 @ 80M
  //   Qr   [2,32,2048,128] bf16 @ 128M
  //   Kr   [2,8,2048,128]  bf16 @ 160M
  //   Vtg  [2,8,128,2048]  bf16 @ 168M   total 176 MiB
  char* ws = (char*)d_ws;
  if (ws_size < 184549376u) return;
  bf16* Xb = (bf16*)(ws);
  bf16* Wqkv = (bf16*)(ws + 33554432u);
  bf16* QKV = (bf16*)(ws + 83886080u);
  bf16* Qr = (bf16*)(ws + 134217728u);
  bf16* Kr = (bf16*)(ws + 167772160u);
  bf16* Vtg = (bf16*)(ws + 176160768u);
  bf16* AttnO = Xb;
  bf16* Wob = Wqkv;

  k_cvt<<<8192, 256, 0, stream>>>(hidden, Xb, 2097152);
  k_cvtw3<<<12288, 256, 0, stream>>>(Wq, Wk, Wv, Wqkv);
  // QKV GEMM: 16 x 24 = 384 blocks (256^2 tiles, compiler-scheduled phases)
  k_gemmCS<bf16><<<384, 512, 0, stream>>>(Xb, Wqkv, QKV, 4096, 6144, 24);
  k_rope<<<5120, 256, 0, stream>>>(QKV, Qr, Kr);
  k_vtrans<<<1024, 256, 0, stream>>>(QKV, Vtg);
  k_cvt<<<8192, 256, 0, stream>>>(Wo, Wob, 2097152);
  k_flash<<<512, 256, 0, stream>>>(Qr, Kr, Vtg, AttnO);
  // O-proj: 16 x 16 = 256 blocks (one dispatch wave)
  k_gemmCS<float><<<256, 512, 0, stream>>>(AttnO, Wob, out, 4096, 4096, 16);
}